// Round 2
// 1161.509 us; speedup vs baseline: 1.4253x; 1.4253x over previous
//
#include <hip/hip_runtime.h>
#include <hip/hip_bf16.h>

// Qwen3-Next GatedDeltaNet prefill, B=2, S=2048, HK=16, HV=32, DK=DV=128, K=4.
// Round 6 (= round-5 resubmit; previous bench died on container acquire):
//  - 16-token chunks DMA'd into a double-buffered 34 KB LDS ring via
//    global_load_lds (19 instrs/chunk), counted s_waitcnt vmcnt(35) so the
//    next chunk's loads stay in flight across a whole chunk of compute.
//  - compute reads K/Q granules in (r ^ (kh>>1)) order -> bank-conflict-free
//    ds_read_b128 (static register indices; permutation absorbed by dots).
//  - step_tok: decay folded into pred*eg and fma(eg,S,k*delta): ~65 VALU/tok.
// Preproc: 4 tokens/block with rolling conv history; gating packs (eg, beta).

#define B_    2
#define S_    2048
#define HK_   16
#define HV_   32
#define DK_   128
#define QKV_  8192
#define EPS_  1e-6f
#define SCALE_ 0.08838834764831845f   // 128^-0.5
#define CH_   16
#define NCH_  (S_ / CH_)

#define AS_GLOBAL __attribute__((address_space(1)))
#define AS_LDS    __attribute__((address_space(3)))

__device__ __forceinline__ void gload16(const float* src, float* dst) {
    __builtin_amdgcn_global_load_lds((const AS_GLOBAL void*)src,
                                     (AS_LDS void*)dst, 16, 0, 0);
}
__device__ __forceinline__ void gload4(const float* src, float* dst) {
    __builtin_amdgcn_global_load_lds((const AS_GLOBAL void*)src,
                                     (AS_LDS void*)dst, 4, 0, 0);
}

// ---------------------------------------------------------------------------
// Preprocess: y = silu(causal_conv(x)); q/k l2-normalized per 128-ch head,
// q pre-scaled by DK^-0.5. Y layout = x layout: [B*S, 8192].
// grid (4 segs, B*S/4), block 256, 8 ch/thread, 4 tokens/block (rolling hist).
// ---------------------------------------------------------------------------
__global__ __launch_bounds__(256)
void preproc_kernel(const float* __restrict__ x, const float* __restrict__ w,
                    float* __restrict__ Y)
{
    const int seg = blockIdx.x;            // 0:q 1:k 2,3:v
    const int bt0 = blockIdx.y * 4;        // first global row of this block
    const int t0  = bt0 & (S_ - 1);        // token within sequence
    const int tid = threadIdx.x;
    const int c0  = seg * 2048 + tid * 8;

    float4 w4[8];
#pragma unroll
    for (int i = 0; i < 8; ++i)
        w4[i] = *reinterpret_cast<const float4*>(&w[(c0 + i) * 4]);

    float h0[8], h1[8], h2[8], cur[8], y[8];

#pragma unroll
    for (int i = 0; i < 8; ++i) { h0[i] = 0.f; h1[i] = 0.f; h2[i] = 0.f; }
    if (t0 >= 3) {   // t0 is a multiple of 4, so either 0 (all zero) or >=4
        const float* r0 = &x[(size_t)(bt0 - 3) * QKV_ + c0];
        const float* r1 = &x[(size_t)(bt0 - 2) * QKV_ + c0];
        const float* r2 = &x[(size_t)(bt0 - 1) * QKV_ + c0];
#pragma unroll
        for (int i4 = 0; i4 < 2; ++i4) {
            const float4 a = *reinterpret_cast<const float4*>(r0 + i4 * 4);
            const float4 b = *reinterpret_cast<const float4*>(r1 + i4 * 4);
            const float4 c = *reinterpret_cast<const float4*>(r2 + i4 * 4);
            h0[4*i4+0]=a.x; h0[4*i4+1]=a.y; h0[4*i4+2]=a.z; h0[4*i4+3]=a.w;
            h1[4*i4+0]=b.x; h1[4*i4+1]=b.y; h1[4*i4+2]=b.z; h1[4*i4+3]=b.w;
            h2[4*i4+0]=c.x; h2[4*i4+1]=c.y; h2[4*i4+2]=c.z; h2[4*i4+3]=c.w;
        }
    }

#pragma unroll
    for (int tt = 0; tt < 4; ++tt) {
        const float* rc = &x[(size_t)(bt0 + tt) * QKV_ + c0];
#pragma unroll
        for (int i4 = 0; i4 < 2; ++i4) {
            const float4 a = *reinterpret_cast<const float4*>(rc + i4 * 4);
            cur[4*i4+0]=a.x; cur[4*i4+1]=a.y; cur[4*i4+2]=a.z; cur[4*i4+3]=a.w;
        }
#pragma unroll
        for (int i = 0; i < 8; ++i) {
            float v = h0[i]*w4[i].x + h1[i]*w4[i].y + h2[i]*w4[i].z + cur[i]*w4[i].w;
            y[i] = v / (1.f + expf(-v));                 // silu
        }
        if (seg < 2) {                                    // l2norm over 128 ch = 16 lanes
            float s = 0.f;
#pragma unroll
            for (int i = 0; i < 8; ++i) s += y[i] * y[i];
#pragma unroll
            for (int off = 8; off >= 1; off >>= 1)
                s += __shfl_xor(s, off, 64);
            float rn = rsqrtf(s + EPS_);
            if (seg == 0) rn *= SCALE_;
#pragma unroll
            for (int i = 0; i < 8; ++i) y[i] *= rn;
        }
        float4* dst = reinterpret_cast<float4*>(&Y[(size_t)(bt0 + tt) * QKV_ + c0]);
        dst[0] = make_float4(y[0], y[1], y[2], y[3]);
        dst[1] = make_float4(y[4], y[5], y[6], y[7]);
#pragma unroll
        for (int i = 0; i < 8; ++i) { h0[i] = h1[i]; h1[i] = h2[i]; h2[i] = cur[i]; }
    }
}

// ---------------------------------------------------------------------------
// Gating: GB[i] = (exp(-exp(alog)*softplus(a+dt_bias)), sigmoid(b)). [B*S,HV]
// ---------------------------------------------------------------------------
__global__ __launch_bounds__(256)
void gating_kernel(const float* __restrict__ bin, const float* __restrict__ ain,
                   const float* __restrict__ dtb, const float* __restrict__ alg,
                   float2* __restrict__ GB)
{
    const int i = blockIdx.x * 256 + threadIdx.x;
    if (i >= B_ * S_ * HV_) return;
    const int h = i & (HV_ - 1);
    const float av = ain[i] + dtb[h];
    const float sp = (av > 20.f) ? av : log1pf(expf(av));
    GB[i] = make_float2(expf(-expf(alg[h]) * sp), 1.f / (1.f + expf(-bin[i])));
}

// ---------------------------------------------------------------------------
// Recurrence helpers
// ---------------------------------------------------------------------------
__device__ __forceinline__ void lds_load(const float* __restrict__ Kt,
                                         const float* __restrict__ Qt,
                                         const float* __restrict__ Vt,
                                         const float* __restrict__ Gt,
                                         int kh, int vloc, int sw,
                                         float (&kf)[16], float (&qf)[16],
                                         float& vv, float2& g)
{
    // read granules in order (r ^ sw): per-instruction lane granules are
    // distinct mod 8 -> conflict-free ds_read_b128. Register indices STATIC;
    // the per-thread granule permutation is shared by kf/qf/S so all dot
    // products and elementwise updates stay consistent.
#pragma unroll
    for (int r = 0; r < 4; ++r) {
        const int idx = r ^ sw;                           // LDS address only
        const float4 kq = *reinterpret_cast<const float4*>(Kt + kh * 16 + idx * 4);
        const float4 qq = *reinterpret_cast<const float4*>(Qt + kh * 16 + idx * 4);
        kf[4*r+0]=kq.x; kf[4*r+1]=kq.y; kf[4*r+2]=kq.z; kf[4*r+3]=kq.w;
        qf[4*r+0]=qq.x; qf[4*r+1]=qq.y; qf[4*r+2]=qq.z; qf[4*r+3]=qq.w;
    }
    vv = Vt[vloc];
    g  = *reinterpret_cast<const float2*>(Gt);
}

__device__ __forceinline__ void step_tok(float (&S)[16],
                                         const float (&kf)[16], const float (&qf)[16],
                                         float vv, float2 g, int kh,
                                         float* __restrict__ optr)
{
    const float eg = g.x, bt = g.y;
    // pred = eg * dot(k, S_old)   (decay folded out of the first pass)
    float p0 = 0.f, p1 = 0.f, p2 = 0.f, p3 = 0.f;
#pragma unroll
    for (int j = 0; j < 16; j += 4) {
        p0 += kf[j+0] * S[j+0];
        p1 += kf[j+1] * S[j+1];
        p2 += kf[j+2] * S[j+2];
        p3 += kf[j+3] * S[j+3];
    }
    float pred = (p0 + p1) + (p2 + p3);
    pred += __shfl_xor(pred, 1, 64);
    pred += __shfl_xor(pred, 2, 64);
    pred += __shfl_xor(pred, 4, 64);
    const float delta = bt * (vv - pred * eg);

    // S = eg*S + k*delta ; o = dot(q, S_new)
    float o0 = 0.f, o1 = 0.f, o2 = 0.f, o3 = 0.f;
#pragma unroll
    for (int j = 0; j < 16; j += 4) {
        float s0 = fmaf(eg, S[j+0], kf[j+0] * delta); S[j+0] = s0; o0 += qf[j+0] * s0;
        float s1 = fmaf(eg, S[j+1], kf[j+1] * delta); S[j+1] = s1; o1 += qf[j+1] * s1;
        float s2 = fmaf(eg, S[j+2], kf[j+2] * delta); S[j+2] = s2; o2 += qf[j+2] * s2;
        float s3 = fmaf(eg, S[j+3], kf[j+3] * delta); S[j+3] = s3; o3 += qf[j+3] * s3;
    }
    float o = (o0 + o1) + (o2 + o3);
    o += __shfl_xor(o, 1, 64);
    o += __shfl_xor(o, 2, 64);
    o += __shfl_xor(o, 4, 64);
    if (kh == 0) *optr = o;
}

// ---------------------------------------------------------------------------
// Recurrence: grid (HV, B, 16 v-slices) = 1024 single-wave blocks, 64 threads.
// thread = (vcol = vs*8 + lane>>3, kh = lane&7); owns S[kh*16 .. +15][vcol].
// 16-token chunks staged to LDS (double-buffered) via global_load_lds; the
// chunk c+2 DMA is issued after computing chunk c and kept in flight with
// s_waitcnt vmcnt(35) = 19 loads + 16 o-stores (in-order vmcnt retirement
// guarantees chunk c+1's older loads have landed).
// ---------------------------------------------------------------------------
__global__ __launch_bounds__(64, 1)
void recur_kernel(const float* __restrict__ Y, const float2* __restrict__ GB,
                  float* __restrict__ out)
{
    const int h    = blockIdx.x;
    const int b    = blockIdx.y;
    const int vs   = blockIdx.z;
    const int hk   = h >> 1;
    const int lane = threadIdx.x;
    const int kh   = lane & 7;
    const int vloc = lane >> 3;
    const int sw   = kh >> 1;

    const int qoff0 = hk * DK_;
    const int koff0 = 2048 + hk * DK_;
    const int voff0 = 4096 + h * DK_ + vs * 8;

    // 34304 B static LDS -> 4 blocks/CU co-resident (4*34304 <= 160 KiB)
    __shared__ __align__(16) float Ksm[2][CH_][128];
    __shared__ __align__(16) float Qsm[2][CH_][128];
    __shared__ __align__(16) float Vsm[2][CH_ * 8];
    __shared__ __align__(16) float Gsm[2][64];

    const float* rowBase = Y + (size_t)(b * S_) * QKV_;
    const float* gflat   = (const float*)(GB + (size_t)(b * S_) * HV_ + h);
    float* obase = out + ((size_t)(b * S_) * HV_ + h) * (size_t)DK_ + vs * 8 + vloc;

    // DMA lane roles
    const int tk = lane >> 5;      // K/Q: which of 2 tokens per 1 KiB instr
    const int gr = lane & 31;      // 16-B granule within a 512-B row

    auto issue_chunk = [&](int t0, int bsel) {
#pragma unroll
        for (int i = 0; i < 8; ++i)     // K: 8 x 16B, 2 tokens each
            gload16(rowBase + (size_t)(t0 + 2 * i + tk) * QKV_ + koff0 + gr * 4,
                    &Ksm[bsel][2 * i][0]);
#pragma unroll
        for (int i = 0; i < 8; ++i)     // Q: 8 x 16B
            gload16(rowBase + (size_t)(t0 + 2 * i + tk) * QKV_ + qoff0 + gr * 4,
                    &Qsm[bsel][2 * i][0]);
#pragma unroll
        for (int i = 0; i < 2; ++i)     // V: 2 x 4B, 8 tokens each
            gload4(rowBase + (size_t)(t0 + i * 8 + (lane >> 3)) * QKV_
                           + voff0 + (lane & 7),
                   &Vsm[bsel][i * 64]);
        // G: 1 x 4B; lanes >=32 duplicate into padding
        gload4(gflat + (size_t)(t0 + ((lane >> 1) & 15)) * (HV_ * 2) + (lane & 1),
               &Gsm[bsel][0]);
    };

    float S[16];
#pragma unroll
    for (int j = 0; j < 16; ++j) S[j] = 0.f;

    issue_chunk(0, 0);
    issue_chunk(CH_, 1);
    asm volatile("s_waitcnt vmcnt(19)" ::: "memory");   // chunk 0 landed

    float kA[16], qA[16], vA, kB[16], qB[16], vB;
    float2 gA, gB2;

    for (int c = 0; c < NCH_; ++c) {
        const int bsel = c & 1;
        const int t0   = c * CH_;
        const float (*Kc)[128] = Ksm[bsel];
        const float (*Qc)[128] = Qsm[bsel];
        const float* Vc = Vsm[bsel];
        const float* Gc = Gsm[bsel];

        lds_load(Kc[0], Qc[0], Vc + 0, Gc + 0, kh, vloc, sw, kA, qA, vA, gA);
        lds_load(Kc[1], Qc[1], Vc + 8, Gc + 2, kh, vloc, sw, kB, qB, vB, gB2);
#pragma unroll
        for (int tt = 0; tt < CH_; tt += 2) {
            step_tok(S, kA, qA, vA, gA, kh,
                     obase + (size_t)(t0 + tt) * (HV_ * DK_));
            if (tt + 2 < CH_)
                lds_load(Kc[tt + 2], Qc[tt + 2], Vc + (tt + 2) * 8, Gc + (tt + 2) * 2,
                         kh, vloc, sw, kA, qA, vA, gA);
            __builtin_amdgcn_sched_barrier(0);   // pin refill-A ahead of step-B
            step_tok(S, kB, qB, vB, gB2, kh,
                     obase + (size_t)(t0 + tt + 1) * (HV_ * DK_));
            if (tt + 3 < CH_)
                lds_load(Kc[tt + 3], Qc[tt + 3], Vc + (tt + 3) * 8, Gc + (tt + 3) * 2,
                         kh, vloc, sw, kB, qB, vB, gB2);
        }

        // prefetch chunk c+2 into the buffer we just finished reading
        const int tn = (c + 2 < NCH_) ? (c + 2) * CH_ : (NCH_ - 1) * CH_;
        issue_chunk(tn, bsel);
        // keep the newest 35 vmem ops (19 DMA + 16 o-stores) in flight; all
        // older ops -- incl. chunk c+1's DMA -- are retired in order.
        asm volatile("s_waitcnt vmcnt(35)" ::: "memory");
    }
}

// ---------------------------------------------------------------------------
// Fallback (round-2 monolithic kernel) if workspace is too small.
// ---------------------------------------------------------------------------
__global__ __launch_bounds__(128)
void gdn_prefill_fallback(const float* __restrict__ xqkv, const float* __restrict__ bin,
                          const float* __restrict__ ain, const float* __restrict__ wconv,
                          const float* __restrict__ dtb, const float* __restrict__ alg,
                          float* __restrict__ out)
{
    const int h = blockIdx.x, b = blockIdx.y;
    const int hk = h >> 1;
    const int tid = threadIdx.x, lane = tid & 63, wid = tid >> 6;
    __shared__ __align__(16) float ks[DK_];
    __shared__ __align__(16) float qs[DK_];
    __shared__ float redq[2], redk[2];
    const int qc = hk * DK_ + tid, kc = HK_ * DK_ + hk * DK_ + tid,
              vc = 2 * HK_ * DK_ + h * DK_ + tid;
    float wq[4], wk[4], wv[4];
#pragma unroll
    for (int j = 0; j < 4; ++j) {
        wq[j] = wconv[qc*4+j]; wk[j] = wconv[kc*4+j]; wv[j] = wconv[vc*4+j];
    }
    const float nea = -expf(alg[h]), dbi = dtb[h];
    float hq0=0,hq1=0,hq2=0,hk0=0,hk1=0,hk2=0,hv0=0,hv1=0,hv2=0;
    float Sr[DK_];
#pragma unroll
    for (int k = 0; k < DK_; ++k) Sr[k] = 0.f;
    const size_t row0 = (size_t)b * S_;
    for (int t = 0; t < S_; ++t) {
        const size_t row = row0 + t, xb = row * QKV_;
        const float xq = xqkv[xb+qc], xk = xqkv[xb+kc], xv = xqkv[xb+vc];
        float yq = hq0*wq[0]+hq1*wq[1]+hq2*wq[2]+xq*wq[3];
        float yk = hk0*wk[0]+hk1*wk[1]+hk2*wk[2]+xk*wk[3];
        float yv = hv0*wv[0]+hv1*wv[1]+hv2*wv[2]+xv*wv[3];
        hq0=hq1;hq1=hq2;hq2=xq; hk0=hk1;hk1=hk2;hk2=xk; hv0=hv1;hv1=hv2;hv2=xv;
        yq = yq/(1.f+expf(-yq)); yk = yk/(1.f+expf(-yk)); yv = yv/(1.f+expf(-yv));
        float sq = yq*yq, sk = yk*yk;
#pragma unroll
        for (int off = 32; off >= 1; off >>= 1) {
            sq += __shfl_xor(sq, off, 64); sk += __shfl_xor(sk, off, 64);
        }
        if (lane == 0) { redq[wid] = sq; redk[wid] = sk; }
        __syncthreads();
        const float qn = yq * rsqrtf(redq[0]+redq[1]+EPS_) * SCALE_;
        const float kn = yk * rsqrtf(redk[0]+redk[1]+EPS_);
        ks[tid] = kn; qs[tid] = qn;
        const size_t rab = row * HV_ + h;
        const float av = ain[rab] + dbi;
        const float sp = (av > 20.f) ? av : log1pf(expf(av));
        const float eg = expf(nea * sp);
        const float beta = 1.f/(1.f+expf(-bin[rab]));
        __syncthreads();
        float pred = 0.f;
#pragma unroll
        for (int k4 = 0; k4 < DK_/4; ++k4) {
            const float4 kv = *reinterpret_cast<const float4*>(&ks[k4*4]);
            float s;
            s = Sr[4*k4+0]*eg; Sr[4*k4+0]=s; pred += kv.x*s;
            s = Sr[4*k4+1]*eg; Sr[4*k4+1]=s; pred += kv.y*s;
            s = Sr[4*k4+2]*eg; Sr[4*k4+2]=s; pred += kv.z*s;
            s = Sr[4*k4+3]*eg; Sr[4*k4+3]=s; pred += kv.w*s;
        }
        const float delta = beta * (yv - pred);
        float o = 0.f;
#pragma unroll
        for (int k4 = 0; k4 < DK_/4; ++k4) {
            const float4 kv = *reinterpret_cast<const float4*>(&ks[k4*4]);
            const float4 qv = *reinterpret_cast<const float4*>(&qs[k4*4]);
            float s;
            s = Sr[4*k4+0]+kv.x*delta; Sr[4*k4+0]=s; o += qv.x*s;
            s = Sr[4*k4+1]+kv.y*delta; Sr[4*k4+1]=s; o += qv.y*s;
            s = Sr[4*k4+2]+kv.z*delta; Sr[4*k4+2]=s; o += qv.z*s;
            s = Sr[4*k4+3]+kv.w*delta; Sr[4*k4+3]=s; o += qv.w*s;
        }
        out[rab * DK_ + tid] = o;
    }
}

extern "C" void kernel_launch(void* const* d_in, const int* in_sizes, int n_in,
                              void* d_out, int out_size, void* d_ws, size_t ws_size,
                              hipStream_t stream) {
    const float* xqkv  = (const float*)d_in[0];
    const float* bin   = (const float*)d_in[1];
    const float* ain   = (const float*)d_in[2];
    const float* wconv = (const float*)d_in[3];
    const float* dtb   = (const float*)d_in[4];
    const float* alg   = (const float*)d_in[5];
    float* out = (float*)d_out;

    const size_t Y_BYTES = (size_t)B_ * S_ * QKV_ * 4;         // 134 MB
    const size_t G_BYTES = (size_t)B_ * S_ * HV_ * 8;          // 1 MB (float2)
    const size_t NEEDED  = Y_BYTES + G_BYTES;

    if (ws_size >= NEEDED) {
        float*  Y  = (float*)d_ws;
        float2* GB = (float2*)((char*)d_ws + Y_BYTES);

        preproc_kernel<<<dim3(4, B_ * S_ / 4), 256, 0, stream>>>(xqkv, wconv, Y);
        gating_kernel<<<dim3((B_ * S_ * HV_ + 255) / 256), 256, 0, stream>>>(
            bin, ain, dtb, alg, GB);
        recur_kernel<<<dim3(HV_, B_, 16), 64, 0, stream>>>(Y, GB, out);
    } else {
        gdn_prefill_fallback<<<dim3(HV_, B_), 128, 0, stream>>>(
            xqkv, bin, ain, wconv, dtb, alg, out);
    }
}

// Round 3
// 821.023 us; speedup vs baseline: 2.0164x; 1.4147x over previous
//
#include <hip/hip_runtime.h>
#include <hip/hip_bf16.h>

// Qwen3-Next GatedDeltaNet prefill, B=2, S=2048, HK=16, HV=32, DK=DV=128, K=4.
// Round 7: DPP reductions. rocprof showed recur at 1157 cy/token with only
// 33% VALUBusy and nothing else saturated -> ~775 cy/token dependency stall.
// The pred/o 8-lane reductions used __shfl_xor -> ds_bpermute (~120cy LDS-pipe
// latency each, 3 serial on the token-recurrence critical path). Replaced with
// VALU-latency DPP adds: xor1=quad_perm[1,0,3,2](0xB1), xor2=quad_perm[2,3,0,1]
// (0x4E), xor4=row_half_mirror(0x141; valid since quad lanes are uniform after
// stages 1-2). Everything else identical to round 6 (LDS ring, vmcnt(35)).

#define B_    2
#define S_    2048
#define HK_   16
#define HV_   32
#define DK_   128
#define QKV_  8192
#define EPS_  1e-6f
#define SCALE_ 0.08838834764831845f   // 128^-0.5
#define CH_   16
#define NCH_  (S_ / CH_)

#define AS_GLOBAL __attribute__((address_space(1)))
#define AS_LDS    __attribute__((address_space(3)))

__device__ __forceinline__ void gload16(const float* src, float* dst) {
    __builtin_amdgcn_global_load_lds((const AS_GLOBAL void*)src,
                                     (AS_LDS void*)dst, 16, 0, 0);
}
__device__ __forceinline__ void gload4(const float* src, float* dst) {
    __builtin_amdgcn_global_load_lds((const AS_GLOBAL void*)src,
                                     (AS_LDS void*)dst, 4, 0, 0);
}

// 8-lane sum over lanes sharing (lane>>3): all stages VALU-latency DPP.
__device__ __forceinline__ float red8(float x) {
    int t;
    t = __builtin_amdgcn_update_dpp(0, __float_as_int(x), 0xB1, 0xF, 0xF, true);
    x += __int_as_float(t);                               // + lane^1
    t = __builtin_amdgcn_update_dpp(0, __float_as_int(x), 0x4E, 0xF, 0xF, true);
    x += __int_as_float(t);                               // + lane^2
    t = __builtin_amdgcn_update_dpp(0, __float_as_int(x), 0x141, 0xF, 0xF, true);
    x += __int_as_float(t);                               // + lane^4 (via ^7)
    return x;
}

// ---------------------------------------------------------------------------
// Preprocess: y = silu(causal_conv(x)); q/k l2-normalized per 128-ch head,
// q pre-scaled by DK^-0.5. Y layout = x layout: [B*S, 8192].
// grid (4 segs, B*S/4), block 256, 8 ch/thread, 4 tokens/block (rolling hist).
// ---------------------------------------------------------------------------
__global__ __launch_bounds__(256)
void preproc_kernel(const float* __restrict__ x, const float* __restrict__ w,
                    float* __restrict__ Y)
{
    const int seg = blockIdx.x;            // 0:q 1:k 2,3:v
    const int bt0 = blockIdx.y * 4;        // first global row of this block
    const int t0  = bt0 & (S_ - 1);        // token within sequence
    const int tid = threadIdx.x;
    const int c0  = seg * 2048 + tid * 8;

    float4 w4[8];
#pragma unroll
    for (int i = 0; i < 8; ++i)
        w4[i] = *reinterpret_cast<const float4*>(&w[(c0 + i) * 4]);

    float h0[8], h1[8], h2[8], cur[8], y[8];

#pragma unroll
    for (int i = 0; i < 8; ++i) { h0[i] = 0.f; h1[i] = 0.f; h2[i] = 0.f; }
    if (t0 >= 3) {   // t0 is a multiple of 4, so either 0 (all zero) or >=4
        const float* r0 = &x[(size_t)(bt0 - 3) * QKV_ + c0];
        const float* r1 = &x[(size_t)(bt0 - 2) * QKV_ + c0];
        const float* r2 = &x[(size_t)(bt0 - 1) * QKV_ + c0];
#pragma unroll
        for (int i4 = 0; i4 < 2; ++i4) {
            const float4 a = *reinterpret_cast<const float4*>(r0 + i4 * 4);
            const float4 b = *reinterpret_cast<const float4*>(r1 + i4 * 4);
            const float4 c = *reinterpret_cast<const float4*>(r2 + i4 * 4);
            h0[4*i4+0]=a.x; h0[4*i4+1]=a.y; h0[4*i4+2]=a.z; h0[4*i4+3]=a.w;
            h1[4*i4+0]=b.x; h1[4*i4+1]=b.y; h1[4*i4+2]=b.z; h1[4*i4+3]=b.w;
            h2[4*i4+0]=c.x; h2[4*i4+1]=c.y; h2[4*i4+2]=c.z; h2[4*i4+3]=c.w;
        }
    }

#pragma unroll
    for (int tt = 0; tt < 4; ++tt) {
        const float* rc = &x[(size_t)(bt0 + tt) * QKV_ + c0];
#pragma unroll
        for (int i4 = 0; i4 < 2; ++i4) {
            const float4 a = *reinterpret_cast<const float4*>(rc + i4 * 4);
            cur[4*i4+0]=a.x; cur[4*i4+1]=a.y; cur[4*i4+2]=a.z; cur[4*i4+3]=a.w;
        }
#pragma unroll
        for (int i = 0; i < 8; ++i) {
            float v = h0[i]*w4[i].x + h1[i]*w4[i].y + h2[i]*w4[i].z + cur[i]*w4[i].w;
            y[i] = v / (1.f + expf(-v));                 // silu
        }
        if (seg < 2) {                                    // l2norm over 128 ch = 16 lanes
            float s = 0.f;
#pragma unroll
            for (int i = 0; i < 8; ++i) s += y[i] * y[i];
#pragma unroll
            for (int off = 8; off >= 1; off >>= 1)
                s += __shfl_xor(s, off, 64);
            float rn = rsqrtf(s + EPS_);
            if (seg == 0) rn *= SCALE_;
#pragma unroll
            for (int i = 0; i < 8; ++i) y[i] *= rn;
        }
        float4* dst = reinterpret_cast<float4*>(&Y[(size_t)(bt0 + tt) * QKV_ + c0]);
        dst[0] = make_float4(y[0], y[1], y[2], y[3]);
        dst[1] = make_float4(y[4], y[5], y[6], y[7]);
#pragma unroll
        for (int i = 0; i < 8; ++i) { h0[i] = h1[i]; h1[i] = h2[i]; h2[i] = cur[i]; }
    }
}

// ---------------------------------------------------------------------------
// Gating: GB[i] = (exp(-exp(alog)*softplus(a+dt_bias)), sigmoid(b)). [B*S,HV]
// ---------------------------------------------------------------------------
__global__ __launch_bounds__(256)
void gating_kernel(const float* __restrict__ bin, const float* __restrict__ ain,
                   const float* __restrict__ dtb, const float* __restrict__ alg,
                   float2* __restrict__ GB)
{
    const int i = blockIdx.x * 256 + threadIdx.x;
    if (i >= B_ * S_ * HV_) return;
    const int h = i & (HV_ - 1);
    const float av = ain[i] + dtb[h];
    const float sp = (av > 20.f) ? av : log1pf(expf(av));
    GB[i] = make_float2(expf(-expf(alg[h]) * sp), 1.f / (1.f + expf(-bin[i])));
}

// ---------------------------------------------------------------------------
// Recurrence helpers
// ---------------------------------------------------------------------------
__device__ __forceinline__ void lds_load(const float* __restrict__ Kt,
                                         const float* __restrict__ Qt,
                                         const float* __restrict__ Vt,
                                         const float* __restrict__ Gt,
                                         int kh, int vloc, int sw,
                                         float (&kf)[16], float (&qf)[16],
                                         float& vv, float2& g)
{
    // read granules in order (r ^ sw): per-instruction lane granules are
    // distinct mod 8 -> conflict-free ds_read_b128. Register indices STATIC;
    // the per-thread granule permutation is shared by kf/qf/S so all dot
    // products and elementwise updates stay consistent.
#pragma unroll
    for (int r = 0; r < 4; ++r) {
        const int idx = r ^ sw;                           // LDS address only
        const float4 kq = *reinterpret_cast<const float4*>(Kt + kh * 16 + idx * 4);
        const float4 qq = *reinterpret_cast<const float4*>(Qt + kh * 16 + idx * 4);
        kf[4*r+0]=kq.x; kf[4*r+1]=kq.y; kf[4*r+2]=kq.z; kf[4*r+3]=kq.w;
        qf[4*r+0]=qq.x; qf[4*r+1]=qq.y; qf[4*r+2]=qq.z; qf[4*r+3]=qq.w;
    }
    vv = Vt[vloc];
    g  = *reinterpret_cast<const float2*>(Gt);
}

__device__ __forceinline__ void step_tok(float (&S)[16],
                                         const float (&kf)[16], const float (&qf)[16],
                                         float vv, float2 g, int kh,
                                         float* __restrict__ optr)
{
    const float eg = g.x, bt = g.y;
    // pred = eg * dot(k, S_old)   (decay folded out of the first pass)
    float p0 = 0.f, p1 = 0.f, p2 = 0.f, p3 = 0.f;
#pragma unroll
    for (int j = 0; j < 16; j += 4) {
        p0 += kf[j+0] * S[j+0];
        p1 += kf[j+1] * S[j+1];
        p2 += kf[j+2] * S[j+2];
        p3 += kf[j+3] * S[j+3];
    }
    float pred = red8((p0 + p1) + (p2 + p3));
    const float delta = bt * (vv - pred * eg);

    // S = eg*S + k*delta ; o = dot(q, S_new)
    float o0 = 0.f, o1 = 0.f, o2 = 0.f, o3 = 0.f;
#pragma unroll
    for (int j = 0; j < 16; j += 4) {
        float s0 = fmaf(eg, S[j+0], kf[j+0] * delta); S[j+0] = s0; o0 += qf[j+0] * s0;
        float s1 = fmaf(eg, S[j+1], kf[j+1] * delta); S[j+1] = s1; o1 += qf[j+1] * s1;
        float s2 = fmaf(eg, S[j+2], kf[j+2] * delta); S[j+2] = s2; o2 += qf[j+2] * s2;
        float s3 = fmaf(eg, S[j+3], kf[j+3] * delta); S[j+3] = s3; o3 += qf[j+3] * s3;
    }
    float o = red8((o0 + o1) + (o2 + o3));
    if (kh == 0) *optr = o;
}

// ---------------------------------------------------------------------------
// Recurrence: grid (HV, B, 16 v-slices) = 1024 single-wave blocks, 64 threads.
// thread = (vcol = vs*8 + lane>>3, kh = lane&7); owns S[kh*16 .. +15][vcol].
// 16-token chunks staged to LDS (double-buffered) via global_load_lds; the
// chunk c+2 DMA is issued after computing chunk c and kept in flight with
// s_waitcnt vmcnt(35) = 19 loads + 16 o-stores (in-order vmcnt retirement
// guarantees chunk c+1's older loads have landed).
// ---------------------------------------------------------------------------
__global__ __launch_bounds__(64, 1)
void recur_kernel(const float* __restrict__ Y, const float2* __restrict__ GB,
                  float* __restrict__ out)
{
    const int h    = blockIdx.x;
    const int b    = blockIdx.y;
    const int vs   = blockIdx.z;
    const int hk   = h >> 1;
    const int lane = threadIdx.x;
    const int kh   = lane & 7;
    const int vloc = lane >> 3;
    const int sw   = kh >> 1;

    const int qoff0 = hk * DK_;
    const int koff0 = 2048 + hk * DK_;
    const int voff0 = 4096 + h * DK_ + vs * 8;

    // 34304 B static LDS -> 4 blocks/CU co-resident (4*34304 <= 160 KiB)
    __shared__ __align__(16) float Ksm[2][CH_][128];
    __shared__ __align__(16) float Qsm[2][CH_][128];
    __shared__ __align__(16) float Vsm[2][CH_ * 8];
    __shared__ __align__(16) float Gsm[2][64];

    const float* rowBase = Y + (size_t)(b * S_) * QKV_;
    const float* gflat   = (const float*)(GB + (size_t)(b * S_) * HV_ + h);
    float* obase = out + ((size_t)(b * S_) * HV_ + h) * (size_t)DK_ + vs * 8 + vloc;

    // DMA lane roles
    const int tk = lane >> 5;      // K/Q: which of 2 tokens per 1 KiB instr
    const int gr = lane & 31;      // 16-B granule within a 512-B row

    auto issue_chunk = [&](int t0, int bsel) {
#pragma unroll
        for (int i = 0; i < 8; ++i)     // K: 8 x 16B, 2 tokens each
            gload16(rowBase + (size_t)(t0 + 2 * i + tk) * QKV_ + koff0 + gr * 4,
                    &Ksm[bsel][2 * i][0]);
#pragma unroll
        for (int i = 0; i < 8; ++i)     // Q: 8 x 16B
            gload16(rowBase + (size_t)(t0 + 2 * i + tk) * QKV_ + qoff0 + gr * 4,
                    &Qsm[bsel][2 * i][0]);
#pragma unroll
        for (int i = 0; i < 2; ++i)     // V: 2 x 4B, 8 tokens each
            gload4(rowBase + (size_t)(t0 + i * 8 + (lane >> 3)) * QKV_
                           + voff0 + (lane & 7),
                   &Vsm[bsel][i * 64]);
        // G: 1 x 4B; lanes >=32 duplicate into padding
        gload4(gflat + (size_t)(t0 + ((lane >> 1) & 15)) * (HV_ * 2) + (lane & 1),
               &Gsm[bsel][0]);
    };

    float S[16];
#pragma unroll
    for (int j = 0; j < 16; ++j) S[j] = 0.f;

    issue_chunk(0, 0);
    issue_chunk(CH_, 1);
    asm volatile("s_waitcnt vmcnt(19)" ::: "memory");   // chunk 0 landed

    float kA[16], qA[16], vA, kB[16], qB[16], vB;
    float2 gA, gB2;

    for (int c = 0; c < NCH_; ++c) {
        const int bsel = c & 1;
        const int t0   = c * CH_;
        const float (*Kc)[128] = Ksm[bsel];
        const float (*Qc)[128] = Qsm[bsel];
        const float* Vc = Vsm[bsel];
        const float* Gc = Gsm[bsel];

        lds_load(Kc[0], Qc[0], Vc + 0, Gc + 0, kh, vloc, sw, kA, qA, vA, gA);
        lds_load(Kc[1], Qc[1], Vc + 8, Gc + 2, kh, vloc, sw, kB, qB, vB, gB2);
#pragma unroll
        for (int tt = 0; tt < CH_; tt += 2) {
            step_tok(S, kA, qA, vA, gA, kh,
                     obase + (size_t)(t0 + tt) * (HV_ * DK_));
            if (tt + 2 < CH_)
                lds_load(Kc[tt + 2], Qc[tt + 2], Vc + (tt + 2) * 8, Gc + (tt + 2) * 2,
                         kh, vloc, sw, kA, qA, vA, gA);
            __builtin_amdgcn_sched_barrier(0);   // pin refill-A ahead of step-B
            step_tok(S, kB, qB, vB, gB2, kh,
                     obase + (size_t)(t0 + tt + 1) * (HV_ * DK_));
            if (tt + 3 < CH_)
                lds_load(Kc[tt + 3], Qc[tt + 3], Vc + (tt + 3) * 8, Gc + (tt + 3) * 2,
                         kh, vloc, sw, kB, qB, vB, gB2);
        }

        // prefetch chunk c+2 into the buffer we just finished reading
        const int tn = (c + 2 < NCH_) ? (c + 2) * CH_ : (NCH_ - 1) * CH_;
        issue_chunk(tn, bsel);
        // keep the newest 35 vmem ops (19 DMA + 16 o-stores) in flight; all
        // older ops -- incl. chunk c+1's DMA -- are retired in order.
        asm volatile("s_waitcnt vmcnt(35)" ::: "memory");
    }
}

// ---------------------------------------------------------------------------
// Fallback (round-2 monolithic kernel) if workspace is too small.
// ---------------------------------------------------------------------------
__global__ __launch_bounds__(128)
void gdn_prefill_fallback(const float* __restrict__ xqkv, const float* __restrict__ bin,
                          const float* __restrict__ ain, const float* __restrict__ wconv,
                          const float* __restrict__ dtb, const float* __restrict__ alg,
                          float* __restrict__ out)
{
    const int h = blockIdx.x, b = blockIdx.y;
    const int hk = h >> 1;
    const int tid = threadIdx.x, lane = tid & 63, wid = tid >> 6;
    __shared__ __align__(16) float ks[DK_];
    __shared__ __align__(16) float qs[DK_];
    __shared__ float redq[2], redk[2];
    const int qc = hk * DK_ + tid, kc = HK_ * DK_ + hk * DK_ + tid,
              vc = 2 * HK_ * DK_ + h * DK_ + tid;
    float wq[4], wk[4], wv[4];
#pragma unroll
    for (int j = 0; j < 4; ++j) {
        wq[j] = wconv[qc*4+j]; wk[j] = wconv[kc*4+j]; wv[j] = wconv[vc*4+j];
    }
    const float nea = -expf(alg[h]), dbi = dtb[h];
    float hq0=0,hq1=0,hq2=0,hk0=0,hk1=0,hk2=0,hv0=0,hv1=0,hv2=0;
    float Sr[DK_];
#pragma unroll
    for (int k = 0; k < DK_; ++k) Sr[k] = 0.f;
    const size_t row0 = (size_t)b * S_;
    for (int t = 0; t < S_; ++t) {
        const size_t row = row0 + t, xb = row * QKV_;
        const float xq = xqkv[xb+qc], xk = xqkv[xb+kc], xv = xqkv[xb+vc];
        float yq = hq0*wq[0]+hq1*wq[1]+hq2*wq[2]+xq*wq[3];
        float yk = hk0*wk[0]+hk1*wk[1]+hk2*wk[2]+xk*wk[3];
        float yv = hv0*wv[0]+hv1*wv[1]+hv2*wv[2]+xv*wv[3];
        hq0=hq1;hq1=hq2;hq2=xq; hk0=hk1;hk1=hk2;hk2=xk; hv0=hv1;hv1=hv2;hv2=xv;
        yq = yq/(1.f+expf(-yq)); yk = yk/(1.f+expf(-yk)); yv = yv/(1.f+expf(-yv));
        float sq = yq*yq, sk = yk*yk;
#pragma unroll
        for (int off = 32; off >= 1; off >>= 1) {
            sq += __shfl_xor(sq, off, 64); sk += __shfl_xor(sk, off, 64);
        }
        if (lane == 0) { redq[wid] = sq; redk[wid] = sk; }
        __syncthreads();
        const float qn = yq * rsqrtf(redq[0]+redq[1]+EPS_) * SCALE_;
        const float kn = yk * rsqrtf(redk[0]+redk[1]+EPS_);
        ks[tid] = kn; qs[tid] = qn;
        const size_t rab = row * HV_ + h;
        const float av = ain[rab] + dbi;
        const float sp = (av > 20.f) ? av : log1pf(expf(av));
        const float eg = expf(nea * sp);
        const float beta = 1.f/(1.f+expf(-bin[rab]));
        __syncthreads();
        float pred = 0.f;
#pragma unroll
        for (int k4 = 0; k4 < DK_/4; ++k4) {
            const float4 kv = *reinterpret_cast<const float4*>(&ks[k4*4]);
            float s;
            s = Sr[4*k4+0]*eg; Sr[4*k4+0]=s; pred += kv.x*s;
            s = Sr[4*k4+1]*eg; Sr[4*k4+1]=s; pred += kv.y*s;
            s = Sr[4*k4+2]*eg; Sr[4*k4+2]=s; pred += kv.z*s;
            s = Sr[4*k4+3]*eg; Sr[4*k4+3]=s; pred += kv.w*s;
        }
        const float delta = beta * (yv - pred);
        float o = 0.f;
#pragma unroll
        for (int k4 = 0; k4 < DK_/4; ++k4) {
            const float4 kv = *reinterpret_cast<const float4*>(&ks[k4*4]);
            const float4 qv = *reinterpret_cast<const float4*>(&qs[k4*4]);
            float s;
            s = Sr[4*k4+0]+kv.x*delta; Sr[4*k4+0]=s; o += qv.x*s;
            s = Sr[4*k4+1]+kv.y*delta; Sr[4*k4+1]=s; o += qv.y*s;
            s = Sr[4*k4+2]+kv.z*delta; Sr[4*k4+2]=s; o += qv.z*s;
            s = Sr[4*k4+3]+kv.w*delta; Sr[4*k4+3]=s; o += qv.w*s;
        }
        out[rab * DK_ + tid] = o;
    }
}

extern "C" void kernel_launch(void* const* d_in, const int* in_sizes, int n_in,
                              void* d_out, int out_size, void* d_ws, size_t ws_size,
                              hipStream_t stream) {
    const float* xqkv  = (const float*)d_in[0];
    const float* bin   = (const float*)d_in[1];
    const float* ain   = (const float*)d_in[2];
    const float* wconv = (const float*)d_in[3];
    const float* dtb   = (const float*)d_in[4];
    const float* alg   = (const float*)d_in[5];
    float* out = (float*)d_out;

    const size_t Y_BYTES = (size_t)B_ * S_ * QKV_ * 4;         // 134 MB
    const size_t G_BYTES = (size_t)B_ * S_ * HV_ * 8;          // 1 MB (float2)
    const size_t NEEDED  = Y_BYTES + G_BYTES;

    if (ws_size >= NEEDED) {
        float*  Y  = (float*)d_ws;
        float2* GB = (float2*)((char*)d_ws + Y_BYTES);

        preproc_kernel<<<dim3(4, B_ * S_ / 4), 256, 0, stream>>>(xqkv, wconv, Y);
        gating_kernel<<<dim3((B_ * S_ * HV_ + 255) / 256), 256, 0, stream>>>(
            bin, ain, dtb, alg, GB);
        recur_kernel<<<dim3(HV_, B_, 16), 64, 0, stream>>>(Y, GB, out);
    } else {
        gdn_prefill_fallback<<<dim3(HV_, B_), 128, 0, stream>>>(
            xqkv, bin, ain, wconv, dtb, alg, out);
    }
}